// Round 12
// baseline (507.628 us; speedup 1.0000x reference)
//
#include <hip/hip_runtime.h>
#include <hip/hip_bf16.h>

#define N_NODES 100000
#define N_EDGES 1600000
#define HID 64
#define OUT_CH 32

// Deterministic radix partition into dst buckets. Zero global atomics
// (R5: contended global cursors serialize device-wide at ~6 ns/atomic).
#define NB 196           // ceil(100000/512) buckets of 512 consecutive dst nodes
#define P 1024           // partition blocks
#define EPP ((N_EDGES + P - 1) / P)   // 1563 edges per block
#define BKCAP 10240      // LDS csr staging cap (bucket mean 8192, sigma ~90)
#define SAP 66           // bf16 tile pitch (+2 pad: conflict-free row reads)

typedef unsigned short ushort_t;

// bf16 helpers (RNE)
__device__ __forceinline__ ushort_t f2b(float f) {
    union { float f; unsigned u; } un; un.f = f;
    unsigned r = un.u + 0x7FFF + ((un.u >> 16) & 1);
    return (ushort_t)(r >> 16);
}
__device__ __forceinline__ float b2f(ushort_t u) {
    union { unsigned u; float f; } un; un.u = ((unsigned)u) << 16;
    return un.f;
}
__device__ __forceinline__ float blo(unsigned u) {
    union { unsigned u; float f; } un; un.u = u << 16; return un.f;
}
__device__ __forceinline__ float bhi(unsigned u) {
    union { unsigned u; float f; } un; un.u = u & 0xFFFF0000u; return un.f;
}

__device__ __forceinline__ int get_dst(const int* __restrict__ ei, int is64, int e) {
    return is64 ? ((const int2*)ei)[N_EDGES + e].x : ei[N_EDGES + e];
}
__device__ __forceinline__ int get_src(const int* __restrict__ ei, int is64, int e) {
    return is64 ? ((const int2*)ei)[e].x : ei[e];
}

// ---- convert x -> bf16; block CONV_BLOCKS runs the edge-dtype probe -------
#define CONV_BLOCKS ((N_NODES * HID / 4) / 256)   // 6250
__global__ void __launch_bounds__(256) convert_detect_kernel(
        const float* __restrict__ x, ushort_t* __restrict__ xb,
        const int* __restrict__ ei, int* __restrict__ flag) {
    if (blockIdx.x == CONV_BLOCKS) {   // detect: int64 => odd 32-bit words all 0
        int i = threadIdx.x;
        if (i < 64) {
            int v = ei[2 * i + 1];
            unsigned long long ball = __ballot(v == 0);
            if (i == 0) *flag = (ball == ~0ull) ? 1 : 0;
        }
        return;
    }
    int i = blockIdx.x * 256 + threadIdx.x;
    float4 v = ((const float4*)x)[i];
    ushort4 o;
    o.x = f2b(v.x); o.y = f2b(v.y); o.z = f2b(v.z); o.w = f2b(v.w);
    ((ushort4*)xb)[i] = o;
}

// ---- pass 1: per-block bucket histograms ----------------------------------
__global__ void __launch_bounds__(256) hist_kernel(
        const int* __restrict__ ei, const int* __restrict__ flag,
        int* __restrict__ histG) {
    __shared__ int lh[NB];
    int tid = threadIdx.x;
    for (int i = tid; i < NB; i += 256) lh[i] = 0;
    __syncthreads();
    int is64 = *flag;
    int e0 = blockIdx.x * EPP;
    int e1 = min(e0 + EPP, N_EDGES);
    for (int e = e0 + tid; e < e1; e += 256) {
        int d = get_dst(ei, is64, e);
        atomicAdd(&lh[d >> 9], 1);
    }
    __syncthreads();
    for (int i = tid; i < NB; i += 256) histG[i * P + blockIdx.x] = lh[i];
}

// ---- per-bucket exclusive scan over P block-counts (4 elems/thread) -------
__global__ void __launch_bounds__(256) scan_kernel(int* __restrict__ histG,
                                                   int* __restrict__ btot) {
    __shared__ int ps[256];
    int b = blockIdx.x;
    int tid = threadIdx.x;
    int base4 = b * P + 4 * tid;
    int v0 = histG[base4], v1 = histG[base4 + 1], v2 = histG[base4 + 2], v3 = histG[base4 + 3];
    int pv = v0 + v1 + v2 + v3;
    ps[tid] = pv;
    __syncthreads();
    for (int d = 1; d < 256; d <<= 1) {
        int t = (tid >= d) ? ps[tid - d] : 0;
        __syncthreads();
        ps[tid] += t;
        __syncthreads();
    }
    int e = ps[tid] - pv;
    histG[base4] = e; e += v0;
    histG[base4 + 1] = e; e += v1;
    histG[base4 + 2] = e; e += v2;
    histG[base4 + 3] = e;
    if (tid == 255) btot[b] = ps[255];
}

// ---- exclusive scan of 196 bucket totals -> dense bucket bases ------------
__global__ void base_scan_kernel(const int* __restrict__ btot, int* __restrict__ bbase) {
    __shared__ int s[256];
    int tid = threadIdx.x;
    int v = (tid < NB) ? btot[tid] : 0;
    s[tid] = v;
    __syncthreads();
    for (int d = 1; d < 256; d <<= 1) {
        int t = (tid >= d) ? s[tid - d] : 0;
        __syncthreads();
        s[tid] += t;
        __syncthreads();
    }
    if (tid < NB) bbase[tid] = s[tid] - v;
}

// ---- pass 2: place records at deterministic offsets (LDS cursors only) ----
// record = (dst&511)<<17 | src
__global__ void __launch_bounds__(256) place_kernel(
        const int* __restrict__ ei, const int* __restrict__ flag,
        const int* __restrict__ histG, const int* __restrict__ bbase,
        int* __restrict__ bkt) {
    __shared__ int lcur[NB];
    int tid = threadIdx.x;
    for (int i = tid; i < NB; i += 256)
        lcur[i] = bbase[i] + histG[i * P + blockIdx.x];
    __syncthreads();
    int is64 = *flag;
    int e0 = blockIdx.x * EPP;
    int e1 = min(e0 + EPP, N_EDGES);
    for (int e = e0 + tid; e < e1; e += 256) {
        int s = get_src(ei, is64, e);
        int d = get_dst(ei, is64, e);
        int val = ((d & 511) << 17) | s;
        int p = atomicAdd(&lcur[d >> 9], 1);
        bkt[p] = val;
    }
}

// ---- per-bucket csr build in LDS + packed off|deg -------------------------
// offpk[n] = (abs_off & 0x1FFFFF) | (deg << 21)
__global__ void __launch_bounds__(256) bucket_fill_kernel(
        const int* __restrict__ bbase, const int* __restrict__ btot,
        const int* __restrict__ bkt, int* __restrict__ csr,
        unsigned int* __restrict__ offpk) {
    __shared__ int lcnt[512];
    __shared__ int loff[512];
    __shared__ int lcur[512];
    __shared__ int ps[256];
    __shared__ int scsr[BKCAP];
    int b = blockIdx.x;
    int tid = threadIdx.x;
    int base = bbase[b];
    int m = btot[b];
    int n0 = b << 9;
    int nn = min(512, N_NODES - n0);

    lcnt[tid] = 0;
    lcnt[tid + 256] = 0;
    __syncthreads();
    for (int i = tid; i < m; i += 256) atomicAdd(&lcnt[bkt[base + i] >> 17], 1);
    __syncthreads();
    int a0 = lcnt[2 * tid], a1 = lcnt[2 * tid + 1];
    int pv = a0 + a1;
    ps[tid] = pv;
    __syncthreads();
    for (int d = 1; d < 256; d <<= 1) {
        int t = (tid >= d) ? ps[tid - d] : 0;
        __syncthreads();
        ps[tid] += t;
        __syncthreads();
    }
    int excl = ps[tid] - pv;
    loff[2 * tid] = excl;
    loff[2 * tid + 1] = excl + a0;
    lcur[2 * tid] = excl;
    lcur[2 * tid + 1] = excl + a0;
    __syncthreads();
    bool fit = (m <= BKCAP);
    for (int i = tid; i < m; i += 256) {
        int val = bkt[base + i];
        int dl = val >> 17;
        int p = atomicAdd(&lcur[dl], 1);
        if (fit) scsr[p] = val & 0x1FFFF;
        else csr[base + p] = val & 0x1FFFF;
    }
    __syncthreads();
    if (fit)
        for (int i = tid; i < m; i += 256) csr[base + i] = scsr[i];
    for (int i = tid; i < nn; i += 256)
        offpk[n0 + i] = (unsigned int)((base + loff[i]) | (lcnt[i] << 21));
}

// ---- fused SAGE layer: gather tile into LDS, then GEMM, ping-pong I/O -----
// Phase 1: wave w gathers nodes w*16..w*16+15 (R11 4-edge/quarter-wave
// scheme) straight into the sA bf16 tile — aggb round trip (2x12.8 MB/layer)
// deleted. Phase 2: layer_v2 GEMM. hin/hout MUST be distinct buffers (other
// blocks gather-read hin while we write hout).
__global__ void __launch_bounds__(256) sage_fused(
        const ushort_t* __restrict__ hin, const unsigned int* __restrict__ offpk,
        const int* __restrict__ csr,
        const float* __restrict__ Wl, const float* __restrict__ Wr,
        const float* __restrict__ bias, ushort_t* __restrict__ hout) {
    __shared__ float sWl[HID * HID];
    __shared__ float sWr[HID * HID];
    __shared__ ushort_t sA[64 * SAP];
    __shared__ ushort_t sH[64 * SAP];
    __shared__ float sb[HID];
    int tid = threadIdx.x;
    {
        const float4* Wl4 = (const float4*)Wl;
        const float4* Wr4 = (const float4*)Wr;
        float4* sWl4 = (float4*)sWl;
        float4* sWr4 = (float4*)sWr;
        for (int i = tid; i < HID * HID / 4; i += 256) {
            sWl4[i] = Wl4[i];
            sWr4[i] = Wr4[i];
        }
    }
    if (tid < HID) sb[tid] = bias[tid];
    int node0 = blockIdx.x * 64;
    size_t tbase = (size_t)node0 * HID;
    {   // root tile: 512 int4 chunks, 2 per thread (overread -> slack)
        const int4* gh = (const int4*)(hin + tbase);
#pragma unroll
        for (int p = 0; p < 2; ++p) {
            int q = tid + 256 * p;
            int r = q >> 3, u = q & 7;
            *(int4*)(sH + r * SAP + u * 8) = gh[q];
        }
    }

    // gather phase: this wave owns 16 consecutive tile rows
    int wave = tid >> 6, o = tid & 63;
    int q4 = o >> 4;          // quarter 0..3 = edge slot
    int l = o & 15;           // channel group 4l..4l+3
    for (int t = 0; t < 16; ++t) {
        int nl = wave * 16 + t;
        int node = node0 + nl;
        unsigned int v = (node < N_NODES) ? offpk[node] : 0u;  // poisoned ws guard
        int off0 = (int)(v & 0x1FFFFFu);
        int cnt = (int)(v >> 21);
        float a0 = 0.f, a1 = 0.f, a2 = 0.f, a3 = 0.f;
        int base = off0;
        int rem = cnt;
        while (rem > 0) {
            int take = min(rem, 64);
            int idxv = (o < take) ? csr[base + o] : 0;
            int j = 0;
            for (; j + 8 <= take; j += 8) {
                int i0 = __shfl(idxv, j + q4);
                int i1 = __shfl(idxv, j + 4 + q4);
                int2 u0 = ((const int2*)(hin + (size_t)i0 * HID))[l];
                int2 u1 = ((const int2*)(hin + (size_t)i1 * HID))[l];
                a0 += blo(u0.x) + blo(u1.x);
                a1 += bhi(u0.x) + bhi(u1.x);
                a2 += blo(u0.y) + blo(u1.y);
                a3 += bhi(u0.y) + bhi(u1.y);
            }
            for (; j < take; j += 4) {
                int e = j + q4;
                bool valid = (e < take);
                int idx = __shfl(idxv, valid ? e : 0);
                if (valid) {
                    int2 u = ((const int2*)(hin + (size_t)idx * HID))[l];
                    a0 += blo(u.x); a1 += bhi(u.x);
                    a2 += blo(u.y); a3 += bhi(u.y);
                }
            }
            base += take;
            rem -= take;
        }
        a0 += __shfl_xor(a0, 16); a0 += __shfl_xor(a0, 32);
        a1 += __shfl_xor(a1, 16); a1 += __shfl_xor(a1, 32);
        a2 += __shfl_xor(a2, 16); a2 += __shfl_xor(a2, 32);
        a3 += __shfl_xor(a3, 16); a3 += __shfl_xor(a3, 32);
        if (o < 16) {
            float inv = 1.f / fmaxf((float)cnt, 1.f);
            ushort4 w;
            w.x = f2b(a0 * inv); w.y = f2b(a1 * inv);
            w.z = f2b(a2 * inv); w.w = f2b(a3 * inv);
            *(ushort4*)(sA + nl * SAP + l * 4) = w;
        }
    }
    __syncthreads();

    // GEMM phase (layer_v2)
    int c0 = (tid & 15) << 2;
    int n0 = (tid >> 4) << 2;
    float acc[4][4];
#pragma unroll
    for (int i = 0; i < 4; ++i)
#pragma unroll
        for (int j = 0; j < 4; ++j) acc[i][j] = sb[c0 + j];

#pragma unroll 4
    for (int kk = 0; kk < 32; ++kk) {
        float4 wl0 = *(const float4*)&sWl[(2 * kk) * HID + c0];
        float4 wl1 = *(const float4*)&sWl[(2 * kk + 1) * HID + c0];
        float4 wr0 = *(const float4*)&sWr[(2 * kk) * HID + c0];
        float4 wr1 = *(const float4*)&sWr[(2 * kk + 1) * HID + c0];
        const float* wl0p = (const float*)&wl0;
        const float* wl1p = (const float*)&wl1;
        const float* wr0p = (const float*)&wr0;
        const float* wr1p = (const float*)&wr1;
#pragma unroll
        for (int i = 0; i < 4; ++i) {
            unsigned ua = *(const unsigned*)(sA + (n0 + i) * SAP + 2 * kk);
            unsigned uh = *(const unsigned*)(sH + (n0 + i) * SAP + 2 * kk);
            float a0 = blo(ua), a1 = bhi(ua);
            float h0 = blo(uh), h1 = bhi(uh);
#pragma unroll
            for (int j = 0; j < 4; ++j)
                acc[i][j] += a0 * wl0p[j] + a1 * wl1p[j] + h0 * wr0p[j] + h1 * wr1p[j];
        }
    }

#pragma unroll
    for (int i = 0; i < 4; ++i) {
        int n = node0 + n0 + i;
        if (n < N_NODES) {
            ushort4 w;
            w.x = f2b(fmaxf(acc[i][0], 0.f));
            w.y = f2b(fmaxf(acc[i][1], 0.f));
            w.z = f2b(fmaxf(acc[i][2], 0.f));
            w.w = f2b(fmaxf(acc[i][3], 0.f));
            *(ushort4*)(hout + (size_t)n * HID + c0) = w;
        }
    }
}

// ---- head v2: out = h @ Wlin + blin, LDS-tiled, fp32 out ------------------
__global__ void __launch_bounds__(256) head_v2(
        const ushort_t* __restrict__ hb, const float* __restrict__ W,
        const float* __restrict__ bias, float* __restrict__ out) {
    __shared__ float sWo[HID * OUT_CH];
    __shared__ ushort_t sH[64 * SAP];
    __shared__ float sb[OUT_CH];
    int tid = threadIdx.x;
    {
        const float4* W4 = (const float4*)W;
        float4* sW4 = (float4*)sWo;
        for (int i = tid; i < HID * OUT_CH / 4; i += 256) sW4[i] = W4[i];
    }
    if (tid < OUT_CH) sb[tid] = bias[tid];
    size_t tbase = (size_t)blockIdx.x * 64 * HID;
    {
        const int4* gh = (const int4*)(hb + tbase);
#pragma unroll
        for (int p = 0; p < 2; ++p) {
            int q = tid + 256 * p;
            int r = q >> 3, u = q & 7;
            *(int4*)(sH + r * SAP + u * 8) = gh[q];
        }
    }
    __syncthreads();

    int c0 = (tid & 7) << 2;
    int n0 = (tid >> 3) << 1;
    float acc[2][4];
#pragma unroll
    for (int i = 0; i < 2; ++i)
#pragma unroll
        for (int j = 0; j < 4; ++j) acc[i][j] = sb[c0 + j];

#pragma unroll 4
    for (int kk = 0; kk < 32; ++kk) {
        float4 w0 = *(const float4*)&sWo[(2 * kk) * OUT_CH + c0];
        float4 w1 = *(const float4*)&sWo[(2 * kk + 1) * OUT_CH + c0];
        const float* w0p = (const float*)&w0;
        const float* w1p = (const float*)&w1;
#pragma unroll
        for (int i = 0; i < 2; ++i) {
            unsigned uh = *(const unsigned*)(sH + (n0 + i) * SAP + 2 * kk);
            float h0 = blo(uh), h1 = bhi(uh);
#pragma unroll
            for (int j = 0; j < 4; ++j) acc[i][j] += h0 * w0p[j] + h1 * w1p[j];
        }
    }

    int node0 = blockIdx.x * 64;
#pragma unroll
    for (int i = 0; i < 2; ++i) {
        int n = node0 + n0 + i;
        if (n < N_NODES) {
            float4 o4;
            o4.x = acc[i][0]; o4.y = acc[i][1]; o4.z = acc[i][2]; o4.w = acc[i][3];
            *(float4*)(out + (size_t)n * OUT_CH + c0) = o4;
        }
    }
}

extern "C" void kernel_launch(void* const* d_in, const int* in_sizes, int n_in,
                              void* d_out, int out_size, void* d_ws, size_t ws_size,
                              hipStream_t stream) {
    const float* x    = (const float*)d_in[0];
    const int*   ei   = (const int*)d_in[1];
    const float* Wl1  = (const float*)d_in[2];
    const float* Wr1  = (const float*)d_in[3];
    const float* b1   = (const float*)d_in[4];
    const float* Wl2  = (const float*)d_in[5];
    const float* Wr2  = (const float*)d_in[6];
    const float* b2   = (const float*)d_in[7];
    const float* Wl3  = (const float*)d_in[8];
    const float* Wr3  = (const float*)d_in[9];
    const float* b3   = (const float*)d_in[10];
    const float* Wlin = (const float*)d_in[11];
    const float* blin = (const float*)d_in[12];
    float* out = (float*)d_out;

    // workspace layout (4-byte units), ~33 MB; tile overreads land in slack.
    int* ip              = (int*)d_ws;
    int* flag            = ip;                          // 128
    unsigned int* offpk  = (unsigned int*)(flag + 128); // 100096
    int* bbase           = (int*)(offpk + 100096);      // 256
    int* btot            = bbase + 256;                 // 256
    int* histG           = btot + 256;                  // NB*P = 200704
    int* csr             = histG + NB * P;              // 1600000
    ushort_t* bufA       = (ushort_t*)(csr + N_EDGES);  // 6.4M bf16 + 8192 slack
    ushort_t* bufB       = bufA + 6408192;              // 6.4M bf16 + 8192 slack
    int* bkt             = (int*)bufB;  // bucket records alias bufB (dead before L1 writes B)

    const int TILE_BLOCKS = (N_NODES + 63) / 64;        // 1563

    // x -> bf16 into A (+edge dtype probe), then deterministic radix CSR build
    convert_detect_kernel<<<CONV_BLOCKS + 1, 256, 0, stream>>>(x, bufA, ei, flag);
    hist_kernel<<<P, 256, 0, stream>>>(ei, flag, histG);
    scan_kernel<<<NB, 256, 0, stream>>>(histG, btot);
    base_scan_kernel<<<1, 256, 0, stream>>>(btot, bbase);
    place_kernel<<<P, 256, 0, stream>>>(ei, flag, histG, bbase, bkt);
    bucket_fill_kernel<<<NB, 256, 0, stream>>>(bbase, btot, bkt, csr, offpk);

    // fused gather+GEMM layers, ping-pong A->B->A->B
    sage_fused<<<TILE_BLOCKS, 256, 0, stream>>>(bufA, offpk, csr, Wl1, Wr1, b1, bufB);
    sage_fused<<<TILE_BLOCKS, 256, 0, stream>>>(bufB, offpk, csr, Wl2, Wr2, b2, bufA);
    sage_fused<<<TILE_BLOCKS, 256, 0, stream>>>(bufA, offpk, csr, Wl3, Wr3, b3, bufB);

    // head
    head_v2<<<TILE_BLOCKS, 256, 0, stream>>>(bufB, Wlin, blin, out);
}

// Round 13
// 365.519 us; speedup vs baseline: 1.3888x; 1.3888x over previous
//
#include <hip/hip_runtime.h>
#include <hip/hip_bf16.h>

#define N_NODES 100000
#define N_EDGES 1600000
#define HID 64
#define OUT_CH 32

// Deterministic radix partition into dst buckets. Zero global atomics
// (R5: contended global cursors serialize device-wide at ~6 ns/atomic).
// R12 lesson: don't fuse fat-LDS GEMM onto the latency-bound gather.
#define NB 196           // ceil(100000/512) buckets of 512 consecutive dst nodes
#define P 1024           // partition blocks
#define EPP ((N_EDGES + P - 1) / P)   // 1563 edges per block
#define BKCAP 10240      // LDS csr staging cap (bucket mean 8192, sigma ~90)
#define SAP 66           // bf16 tile pitch (+2 pad: conflict-free row reads)

typedef unsigned short ushort_t;

// bf16 helpers (RNE)
__device__ __forceinline__ ushort_t f2b(float f) {
    union { float f; unsigned u; } un; un.f = f;
    unsigned r = un.u + 0x7FFF + ((un.u >> 16) & 1);
    return (ushort_t)(r >> 16);
}
__device__ __forceinline__ float b2f(ushort_t u) {
    union { unsigned u; float f; } un; un.u = ((unsigned)u) << 16;
    return un.f;
}
__device__ __forceinline__ float blo(unsigned u) {
    union { unsigned u; float f; } un; un.u = u << 16; return un.f;
}
__device__ __forceinline__ float bhi(unsigned u) {
    union { unsigned u; float f; } un; un.u = u & 0xFFFF0000u; return un.f;
}

__device__ __forceinline__ int get_dst(const int* __restrict__ ei, int is64, int e) {
    return is64 ? ((const int2*)ei)[N_EDGES + e].x : ei[N_EDGES + e];
}
__device__ __forceinline__ int get_src(const int* __restrict__ ei, int is64, int e) {
    return is64 ? ((const int2*)ei)[e].x : ei[e];
}

// inline edge-dtype probe: int64 => odd 32-bit words all 0 (first wave)
__device__ __forceinline__ void detect_is64(const int* __restrict__ ei,
                                            int* __restrict__ sflag, int tid) {
    if (tid < 64) {
        int v = ei[2 * tid + 1];
        unsigned long long ball = __ballot(v == 0);
        if (tid == 0) *sflag = (ball == ~0ull) ? 1 : 0;
    }
}

// ---- convert x -> bf16 (all 6250 blocks) + bucket histograms (blocks <P) --
#define CONV_BLOCKS ((N_NODES * HID / 4) / 256)   // 6250
__global__ void __launch_bounds__(256) convhist_kernel(
        const float* __restrict__ x, ushort_t* __restrict__ xb,
        const int* __restrict__ ei, int* __restrict__ histG) {
    int i = blockIdx.x * 256 + threadIdx.x;
    if (i < N_NODES * HID / 4) {
        float4 v = ((const float4*)x)[i];
        ushort4 o;
        o.x = f2b(v.x); o.y = f2b(v.y); o.z = f2b(v.z); o.w = f2b(v.w);
        ((ushort4*)xb)[i] = o;
    }
    if (blockIdx.x >= P) return;
    __shared__ int sflag;
    __shared__ int lh[NB];
    int tid = threadIdx.x;
    detect_is64(ei, &sflag, tid);
    for (int k = tid; k < NB; k += 256) lh[k] = 0;
    __syncthreads();
    int is64 = sflag;
    int e0 = blockIdx.x * EPP;
    int e1 = min(e0 + EPP, N_EDGES);
    for (int e = e0 + tid; e < e1; e += 256) {
        int d = get_dst(ei, is64, e);
        atomicAdd(&lh[d >> 9], 1);
    }
    __syncthreads();
    for (int k = tid; k < NB; k += 256) histG[k * P + blockIdx.x] = lh[k];
}

// ---- per-bucket exclusive scan over P block-counts (4 elems/thread) -------
__global__ void __launch_bounds__(256) scan_kernel(int* __restrict__ histG,
                                                   int* __restrict__ btot) {
    __shared__ int ps[256];
    int b = blockIdx.x;
    int tid = threadIdx.x;
    int base4 = b * P + 4 * tid;
    int v0 = histG[base4], v1 = histG[base4 + 1], v2 = histG[base4 + 2], v3 = histG[base4 + 3];
    int pv = v0 + v1 + v2 + v3;
    ps[tid] = pv;
    __syncthreads();
    for (int d = 1; d < 256; d <<= 1) {
        int t = (tid >= d) ? ps[tid - d] : 0;
        __syncthreads();
        ps[tid] += t;
        __syncthreads();
    }
    int e = ps[tid] - pv;
    histG[base4] = e; e += v0;
    histG[base4 + 1] = e; e += v1;
    histG[base4 + 2] = e; e += v2;
    histG[base4 + 3] = e;
    if (tid == 255) btot[b] = ps[255];
}

// ---- place records at deterministic offsets (LDS cursors only) ------------
// Bucket bases computed locally from btot (196-wide LDS scan ~1us; deletes
// the base_scan kernel + its launch boundary). record = (dst&511)<<17 | src
__global__ void __launch_bounds__(256) place_kernel(
        const int* __restrict__ ei, const int* __restrict__ histG,
        const int* __restrict__ btot, int* __restrict__ bkt) {
    __shared__ int lcur[NB];
    __shared__ int ss[256];
    __shared__ int sflag;
    int tid = threadIdx.x;
    detect_is64(ei, &sflag, tid);
    int v = (tid < NB) ? btot[tid] : 0;
    ss[tid] = v;
    __syncthreads();
    for (int d = 1; d < 256; d <<= 1) {
        int t = (tid >= d) ? ss[tid - d] : 0;
        __syncthreads();
        ss[tid] += t;
        __syncthreads();
    }
    if (tid < NB) lcur[tid] = (ss[tid] - v) + histG[tid * P + blockIdx.x];
    __syncthreads();
    int is64 = sflag;
    int e0 = blockIdx.x * EPP;
    int e1 = min(e0 + EPP, N_EDGES);
    for (int e = e0 + tid; e < e1; e += 256) {
        int s = get_src(ei, is64, e);
        int d = get_dst(ei, is64, e);
        int val = ((d & 511) << 17) | s;
        int p = atomicAdd(&lcur[d >> 9], 1);
        bkt[p] = val;
    }
}

// ---- per-bucket csr build in LDS + packed off|deg -------------------------
// offpk[n] = (abs_off & 0x1FFFFF) | (deg << 21); bucket base from local scan.
__global__ void __launch_bounds__(256) bucket_fill_kernel(
        const int* __restrict__ btot, const int* __restrict__ bkt,
        int* __restrict__ csr, unsigned int* __restrict__ offpk) {
    __shared__ int lcnt[512];
    __shared__ int loff[512];
    __shared__ int lcur[512];
    __shared__ int ps[256];
    __shared__ int scsr[BKCAP];
    __shared__ int sbase;
    int b = blockIdx.x;
    int tid = threadIdx.x;
    int m = btot[b];
    // local bucket-base scan
    int vb = (tid < NB) ? btot[tid] : 0;
    ps[tid] = vb;
    __syncthreads();
    for (int d = 1; d < 256; d <<= 1) {
        int t = (tid >= d) ? ps[tid - d] : 0;
        __syncthreads();
        ps[tid] += t;
        __syncthreads();
    }
    if (tid == b) sbase = ps[tid] - vb;   // exclusive prefix at b (b < NB <= 255)
    __syncthreads();
    int base = sbase;
    int n0 = b << 9;
    int nn = min(512, N_NODES - n0);

    lcnt[tid] = 0;
    lcnt[tid + 256] = 0;
    __syncthreads();
    for (int i = tid; i < m; i += 256) atomicAdd(&lcnt[bkt[base + i] >> 17], 1);
    __syncthreads();
    int a0 = lcnt[2 * tid], a1 = lcnt[2 * tid + 1];
    int pv = a0 + a1;
    ps[tid] = pv;
    __syncthreads();
    for (int d = 1; d < 256; d <<= 1) {
        int t = (tid >= d) ? ps[tid - d] : 0;
        __syncthreads();
        ps[tid] += t;
        __syncthreads();
    }
    int excl = ps[tid] - pv;
    loff[2 * tid] = excl;
    loff[2 * tid + 1] = excl + a0;
    lcur[2 * tid] = excl;
    lcur[2 * tid + 1] = excl + a0;
    __syncthreads();
    bool fit = (m <= BKCAP);
    for (int i = tid; i < m; i += 256) {
        int val = bkt[base + i];
        int dl = val >> 17;
        int p = atomicAdd(&lcur[dl], 1);
        if (fit) scsr[p] = val & 0x1FFFF;
        else csr[base + p] = val & 0x1FFFF;
    }
    __syncthreads();
    if (fit)
        for (int i = tid; i < m; i += 256) csr[base + i] = scsr[i];
    for (int i = tid; i < nn; i += 256)
        offpk[n0 + i] = (unsigned int)((base + loff[i]) | (lcnt[i] << 21));
}

// ---- gather: 4 edges per wave-iter, 16-deep unroll (4 int2 loads/lane) ----
__global__ void __launch_bounds__(256) gather_kernel(
        const ushort_t* __restrict__ hb, const unsigned int* __restrict__ offpk,
        const int* __restrict__ csr, ushort_t* __restrict__ aggb) {
    int node = blockIdx.x * 4 + (threadIdx.x >> 6);
    if (node >= N_NODES) return;
    int o = threadIdx.x & 63;
    int q4 = o >> 4;          // quarter 0..3 = edge slot
    int l = o & 15;           // channel group 4l..4l+3
    unsigned int v = offpk[node];
    int off0 = (int)(v & 0x1FFFFFu);
    int cnt = (int)(v >> 21);
    float a0 = 0.f, a1 = 0.f, a2 = 0.f, a3 = 0.f;
    int base = off0;
    int rem = cnt;
    while (rem > 0) {
        int take = min(rem, 64);
        int idxv = (o < take) ? csr[base + o] : 0;
        int j = 0;
        for (; j + 16 <= take; j += 16) {
            int i0 = __shfl(idxv, j + q4);
            int i1 = __shfl(idxv, j + 4 + q4);
            int i2 = __shfl(idxv, j + 8 + q4);
            int i3 = __shfl(idxv, j + 12 + q4);
            int2 u0 = ((const int2*)(hb + (size_t)i0 * HID))[l];
            int2 u1 = ((const int2*)(hb + (size_t)i1 * HID))[l];
            int2 u2 = ((const int2*)(hb + (size_t)i2 * HID))[l];
            int2 u3 = ((const int2*)(hb + (size_t)i3 * HID))[l];
            a0 += (blo(u0.x) + blo(u1.x)) + (blo(u2.x) + blo(u3.x));
            a1 += (bhi(u0.x) + bhi(u1.x)) + (bhi(u2.x) + bhi(u3.x));
            a2 += (blo(u0.y) + blo(u1.y)) + (blo(u2.y) + blo(u3.y));
            a3 += (bhi(u0.y) + bhi(u1.y)) + (bhi(u2.y) + bhi(u3.y));
        }
        for (; j < take; j += 4) {
            int e = j + q4;
            bool valid = (e < take);
            int idx = __shfl(idxv, valid ? e : 0);
            if (valid) {
                int2 u = ((const int2*)(hb + (size_t)idx * HID))[l];
                a0 += blo(u.x); a1 += bhi(u.x);
                a2 += blo(u.y); a3 += bhi(u.y);
            }
        }
        base += take;
        rem -= take;
    }
    a0 += __shfl_xor(a0, 16); a0 += __shfl_xor(a0, 32);
    a1 += __shfl_xor(a1, 16); a1 += __shfl_xor(a1, 32);
    a2 += __shfl_xor(a2, 16); a2 += __shfl_xor(a2, 32);
    a3 += __shfl_xor(a3, 16); a3 += __shfl_xor(a3, 32);
    if (o < 16) {
        float inv = 1.f / fmaxf((float)cnt, 1.f);
        ushort4 w;
        w.x = f2b(a0 * inv); w.y = f2b(a1 * inv);
        w.z = f2b(a2 * inv); w.w = f2b(a3 * inv);
        *(ushort4*)(aggb + (size_t)node * HID + l * 4) = w;
    }
}

// ---- layer v2: relu(agg@Wl + h@Wr + b) -> bf16, conflict-free LDS ---------
__global__ void __launch_bounds__(256) layer_v2(
        const ushort_t* __restrict__ aggb, const ushort_t* __restrict__ rootb,
        const float* __restrict__ Wl, const float* __restrict__ Wr,
        const float* __restrict__ bias, ushort_t* outb) {
    __shared__ float sWl[HID * HID];
    __shared__ float sWr[HID * HID];
    __shared__ ushort_t sA[64 * SAP];
    __shared__ ushort_t sH[64 * SAP];
    __shared__ float sb[HID];
    int tid = threadIdx.x;
    {
        const float4* Wl4 = (const float4*)Wl;
        const float4* Wr4 = (const float4*)Wr;
        float4* sWl4 = (float4*)sWl;
        float4* sWr4 = (float4*)sWr;
        for (int i = tid; i < HID * HID / 4; i += 256) {
            sWl4[i] = Wl4[i];
            sWr4[i] = Wr4[i];
        }
    }
    if (tid < HID) sb[tid] = bias[tid];
    size_t tbase = (size_t)blockIdx.x * 64 * HID;
    {   // 512 int4 chunks, 2 per thread (overread lands in slack)
        const int4* ga = (const int4*)(aggb + tbase);
        const int4* gh = (const int4*)(rootb + tbase);
#pragma unroll
        for (int p = 0; p < 2; ++p) {
            int q = tid + 256 * p;
            int r = q >> 3, u = q & 7;
            *(int4*)(sA + r * SAP + u * 8) = ga[q];
            *(int4*)(sH + r * SAP + u * 8) = gh[q];
        }
    }
    __syncthreads();

    int c0 = (tid & 15) << 2;
    int n0 = (tid >> 4) << 2;
    float acc[4][4];
#pragma unroll
    for (int i = 0; i < 4; ++i)
#pragma unroll
        for (int j = 0; j < 4; ++j) acc[i][j] = sb[c0 + j];

#pragma unroll 4
    for (int kk = 0; kk < 32; ++kk) {
        float4 wl0 = *(const float4*)&sWl[(2 * kk) * HID + c0];
        float4 wl1 = *(const float4*)&sWl[(2 * kk + 1) * HID + c0];
        float4 wr0 = *(const float4*)&sWr[(2 * kk) * HID + c0];
        float4 wr1 = *(const float4*)&sWr[(2 * kk + 1) * HID + c0];
        const float* wl0p = (const float*)&wl0;
        const float* wl1p = (const float*)&wl1;
        const float* wr0p = (const float*)&wr0;
        const float* wr1p = (const float*)&wr1;
#pragma unroll
        for (int i = 0; i < 4; ++i) {
            unsigned ua = *(const unsigned*)(sA + (n0 + i) * SAP + 2 * kk);
            unsigned uh = *(const unsigned*)(sH + (n0 + i) * SAP + 2 * kk);
            float a0 = blo(ua), a1 = bhi(ua);
            float h0 = blo(uh), h1 = bhi(uh);
#pragma unroll
            for (int j = 0; j < 4; ++j)
                acc[i][j] += a0 * wl0p[j] + a1 * wl1p[j] + h0 * wr0p[j] + h1 * wr1p[j];
        }
    }

    int node0 = blockIdx.x * 64;
#pragma unroll
    for (int i = 0; i < 4; ++i) {
        int n = node0 + n0 + i;
        if (n < N_NODES) {
            ushort4 w;
            w.x = f2b(fmaxf(acc[i][0], 0.f));
            w.y = f2b(fmaxf(acc[i][1], 0.f));
            w.z = f2b(fmaxf(acc[i][2], 0.f));
            w.w = f2b(fmaxf(acc[i][3], 0.f));
            *(ushort4*)(outb + (size_t)n * HID + c0) = w;
        }
    }
}

// ---- head v2: out = h @ Wlin + blin, LDS-tiled, fp32 out ------------------
__global__ void __launch_bounds__(256) head_v2(
        const ushort_t* __restrict__ hb, const float* __restrict__ W,
        const float* __restrict__ bias, float* __restrict__ out) {
    __shared__ float sWo[HID * OUT_CH];
    __shared__ ushort_t sH[64 * SAP];
    __shared__ float sb[OUT_CH];
    int tid = threadIdx.x;
    {
        const float4* W4 = (const float4*)W;
        float4* sW4 = (float4*)sWo;
        for (int i = tid; i < HID * OUT_CH / 4; i += 256) sW4[i] = W4[i];
    }
    if (tid < OUT_CH) sb[tid] = bias[tid];
    size_t tbase = (size_t)blockIdx.x * 64 * HID;
    {
        const int4* gh = (const int4*)(hb + tbase);
#pragma unroll
        for (int p = 0; p < 2; ++p) {
            int q = tid + 256 * p;
            int r = q >> 3, u = q & 7;
            *(int4*)(sH + r * SAP + u * 8) = gh[q];
        }
    }
    __syncthreads();

    int c0 = (tid & 7) << 2;
    int n0 = (tid >> 3) << 1;
    float acc[2][4];
#pragma unroll
    for (int i = 0; i < 2; ++i)
#pragma unroll
        for (int j = 0; j < 4; ++j) acc[i][j] = sb[c0 + j];

#pragma unroll 4
    for (int kk = 0; kk < 32; ++kk) {
        float4 w0 = *(const float4*)&sWo[(2 * kk) * OUT_CH + c0];
        float4 w1 = *(const float4*)&sWo[(2 * kk + 1) * OUT_CH + c0];
        const float* w0p = (const float*)&w0;
        const float* w1p = (const float*)&w1;
#pragma unroll
        for (int i = 0; i < 2; ++i) {
            unsigned uh = *(const unsigned*)(sH + (n0 + i) * SAP + 2 * kk);
            float h0 = blo(uh), h1 = bhi(uh);
#pragma unroll
            for (int j = 0; j < 4; ++j) acc[i][j] += h0 * w0p[j] + h1 * w1p[j];
        }
    }

    int node0 = blockIdx.x * 64;
#pragma unroll
    for (int i = 0; i < 2; ++i) {
        int n = node0 + n0 + i;
        if (n < N_NODES) {
            float4 o4;
            o4.x = acc[i][0]; o4.y = acc[i][1]; o4.z = acc[i][2]; o4.w = acc[i][3];
            *(float4*)(out + (size_t)n * OUT_CH + c0) = o4;
        }
    }
}

extern "C" void kernel_launch(void* const* d_in, const int* in_sizes, int n_in,
                              void* d_out, int out_size, void* d_ws, size_t ws_size,
                              hipStream_t stream) {
    const float* x    = (const float*)d_in[0];
    const int*   ei   = (const int*)d_in[1];
    const float* Wl1  = (const float*)d_in[2];
    const float* Wr1  = (const float*)d_in[3];
    const float* b1   = (const float*)d_in[4];
    const float* Wl2  = (const float*)d_in[5];
    const float* Wr2  = (const float*)d_in[6];
    const float* b2   = (const float*)d_in[7];
    const float* Wl3  = (const float*)d_in[8];
    const float* Wr3  = (const float*)d_in[9];
    const float* b3   = (const float*)d_in[10];
    const float* Wlin = (const float*)d_in[11];
    const float* blin = (const float*)d_in[12];
    float* out = (float*)d_out;

    // workspace layout (4-byte units), ~33 MB; tile overreads land in slack.
    int* ip              = (int*)d_ws;
    unsigned int* offpk  = (unsigned int*)ip;           // 100096
    int* btot            = (int*)(offpk + 100096);      // 256
    int* histG           = btot + 256;                  // NB*P = 200704
    int* csr             = histG + NB * P;              // 1600000
    ushort_t* aggb       = (ushort_t*)(csr + N_EDGES);  // 6.4M bf16 + 8192 slack
    ushort_t* featb      = aggb + 6408192;              // 6.4M bf16 + 8192 slack
    int* bkt             = (int*)aggb;  // bucket records alias aggb (dead until gather)

    const int GATHER_BLOCKS = (N_NODES + 3) / 4;         // 25000
    const int TILE_BLOCKS   = (N_NODES + 63) / 64;       // 1563

    // CSR build: convert+hist fused, scan, place, per-bucket fill (11 kernels total)
    convhist_kernel<<<CONV_BLOCKS, 256, 0, stream>>>(x, featb, ei, histG);
    scan_kernel<<<NB, 256, 0, stream>>>(histG, btot);
    place_kernel<<<P, 256, 0, stream>>>(ei, histG, btot, bkt);
    bucket_fill_kernel<<<NB, 256, 0, stream>>>(btot, bkt, csr, offpk);

    // layer 1 (root = bf16 x in featb; in-place featb output is block-local)
    gather_kernel<<<GATHER_BLOCKS, 256, 0, stream>>>(featb, offpk, csr, aggb);
    layer_v2<<<TILE_BLOCKS, 256, 0, stream>>>(aggb, featb, Wl1, Wr1, b1, featb);

    // layer 2
    gather_kernel<<<GATHER_BLOCKS, 256, 0, stream>>>(featb, offpk, csr, aggb);
    layer_v2<<<TILE_BLOCKS, 256, 0, stream>>>(aggb, featb, Wl2, Wr2, b2, featb);

    // layer 3
    gather_kernel<<<GATHER_BLOCKS, 256, 0, stream>>>(featb, offpk, csr, aggb);
    layer_v2<<<TILE_BLOCKS, 256, 0, stream>>>(aggb, featb, Wl3, Wr3, b3, featb);

    // head
    head_v2<<<TILE_BLOCKS, 256, 0, stream>>>(featb, Wlin, blin, out);
}

// Round 14
// 326.458 us; speedup vs baseline: 1.5550x; 1.1197x over previous
//
#include <hip/hip_runtime.h>
#include <hip/hip_bf16.h>

#define N_NODES 100000
#define N_EDGES 1600000
#define HID 64
#define OUT_CH 32

// Deterministic radix partition into dst buckets. Zero global atomics
// (R5: contended global cursors serialize device-wide at ~6 ns/atomic).
// R12 lesson: don't fuse fat-LDS GEMM onto the latency-bound gather.
#define NB 196           // ceil(100000/512) buckets of 512 consecutive dst nodes
#define P 1024           // partition blocks
#define EPP ((N_EDGES + P - 1) / P)   // 1563 edges per block
#define BKCAP 10240      // LDS csr staging cap (bucket mean 8192, sigma ~90)
#define SAP 66           // bf16 tile pitch for head (conflict-free)
#define MP 72            // bf16 tile pitch for MFMA layer (16B-aligned rows)

typedef unsigned short ushort_t;
typedef short bf16x8 __attribute__((ext_vector_type(8)));
typedef float f32x4 __attribute__((ext_vector_type(4)));

// bf16 helpers (RNE)
__device__ __forceinline__ ushort_t f2b(float f) {
    union { float f; unsigned u; } un; un.f = f;
    unsigned r = un.u + 0x7FFF + ((un.u >> 16) & 1);
    return (ushort_t)(r >> 16);
}
__device__ __forceinline__ float b2f(ushort_t u) {
    union { unsigned u; float f; } un; un.u = ((unsigned)u) << 16;
    return un.f;
}
__device__ __forceinline__ float blo(unsigned u) {
    union { unsigned u; float f; } un; un.u = u << 16; return un.f;
}
__device__ __forceinline__ float bhi(unsigned u) {
    union { unsigned u; float f; } un; un.u = u & 0xFFFF0000u; return un.f;
}

__device__ __forceinline__ int get_dst(const int* __restrict__ ei, int is64, int e) {
    return is64 ? ((const int2*)ei)[N_EDGES + e].x : ei[N_EDGES + e];
}
__device__ __forceinline__ int get_src(const int* __restrict__ ei, int is64, int e) {
    return is64 ? ((const int2*)ei)[e].x : ei[e];
}

// inline edge-dtype probe: int64 => odd 32-bit words all 0 (first wave)
__device__ __forceinline__ void detect_is64(const int* __restrict__ ei,
                                            int* __restrict__ sflag, int tid) {
    if (tid < 64) {
        int v = ei[2 * tid + 1];
        unsigned long long ball = __ballot(v == 0);
        if (tid == 0) *sflag = (ball == ~0ull) ? 1 : 0;
    }
}

// ---- convert x -> bf16 (all 6250 blocks) + bucket histograms (blocks <P) --
#define CONV_BLOCKS ((N_NODES * HID / 4) / 256)   // 6250
__global__ void __launch_bounds__(256) convhist_kernel(
        const float* __restrict__ x, ushort_t* __restrict__ xb,
        const int* __restrict__ ei, int* __restrict__ histG) {
    int i = blockIdx.x * 256 + threadIdx.x;
    if (i < N_NODES * HID / 4) {
        float4 v = ((const float4*)x)[i];
        ushort4 o;
        o.x = f2b(v.x); o.y = f2b(v.y); o.z = f2b(v.z); o.w = f2b(v.w);
        ((ushort4*)xb)[i] = o;
    }
    if (blockIdx.x >= P) return;
    __shared__ int sflag;
    __shared__ int lh[NB];
    int tid = threadIdx.x;
    detect_is64(ei, &sflag, tid);
    for (int k = tid; k < NB; k += 256) lh[k] = 0;
    __syncthreads();
    int is64 = sflag;
    int e0 = blockIdx.x * EPP;
    int e1 = min(e0 + EPP, N_EDGES);
    for (int e = e0 + tid; e < e1; e += 256) {
        int d = get_dst(ei, is64, e);
        atomicAdd(&lh[d >> 9], 1);
    }
    __syncthreads();
    for (int k = tid; k < NB; k += 256) histG[k * P + blockIdx.x] = lh[k];
}

// ---- per-bucket exclusive scan over P block-counts (4 elems/thread) -------
__global__ void __launch_bounds__(256) scan_kernel(int* __restrict__ histG,
                                                   int* __restrict__ btot) {
    __shared__ int ps[256];
    int b = blockIdx.x;
    int tid = threadIdx.x;
    int base4 = b * P + 4 * tid;
    int v0 = histG[base4], v1 = histG[base4 + 1], v2 = histG[base4 + 2], v3 = histG[base4 + 3];
    int pv = v0 + v1 + v2 + v3;
    ps[tid] = pv;
    __syncthreads();
    for (int d = 1; d < 256; d <<= 1) {
        int t = (tid >= d) ? ps[tid - d] : 0;
        __syncthreads();
        ps[tid] += t;
        __syncthreads();
    }
    int e = ps[tid] - pv;
    histG[base4] = e; e += v0;
    histG[base4 + 1] = e; e += v1;
    histG[base4 + 2] = e; e += v2;
    histG[base4 + 3] = e;
    if (tid == 255) btot[b] = ps[255];
}

// ---- place records at deterministic offsets (LDS cursors only) ------------
// Bucket bases from local 196-wide scan of btot. record = (dst&511)<<17 | src
__global__ void __launch_bounds__(256) place_kernel(
        const int* __restrict__ ei, const int* __restrict__ histG,
        const int* __restrict__ btot, int* __restrict__ bkt) {
    __shared__ int lcur[NB];
    __shared__ int ss[256];
    __shared__ int sflag;
    int tid = threadIdx.x;
    detect_is64(ei, &sflag, tid);
    int v = (tid < NB) ? btot[tid] : 0;
    ss[tid] = v;
    __syncthreads();
    for (int d = 1; d < 256; d <<= 1) {
        int t = (tid >= d) ? ss[tid - d] : 0;
        __syncthreads();
        ss[tid] += t;
        __syncthreads();
    }
    if (tid < NB) lcur[tid] = (ss[tid] - v) + histG[tid * P + blockIdx.x];
    __syncthreads();
    int is64 = sflag;
    int e0 = blockIdx.x * EPP;
    int e1 = min(e0 + EPP, N_EDGES);
    for (int e = e0 + tid; e < e1; e += 256) {
        int s = get_src(ei, is64, e);
        int d = get_dst(ei, is64, e);
        int val = ((d & 511) << 17) | s;
        int p = atomicAdd(&lcur[d >> 9], 1);
        bkt[p] = val;
    }
}

// ---- per-bucket csr build in LDS + packed off|deg -------------------------
// offpk[n] = (abs_off & 0x1FFFFF) | (deg << 21); bucket base from local scan.
__global__ void __launch_bounds__(256) bucket_fill_kernel(
        const int* __restrict__ btot, const int* __restrict__ bkt,
        int* __restrict__ csr, unsigned int* __restrict__ offpk) {
    __shared__ int lcnt[512];
    __shared__ int loff[512];
    __shared__ int lcur[512];
    __shared__ int ps[256];
    __shared__ int scsr[BKCAP];
    __shared__ int sbase;
    int b = blockIdx.x;
    int tid = threadIdx.x;
    int m = btot[b];
    int vb = (tid < NB) ? btot[tid] : 0;
    ps[tid] = vb;
    __syncthreads();
    for (int d = 1; d < 256; d <<= 1) {
        int t = (tid >= d) ? ps[tid - d] : 0;
        __syncthreads();
        ps[tid] += t;
        __syncthreads();
    }
    if (tid == b) sbase = ps[tid] - vb;   // exclusive prefix at b
    __syncthreads();
    int base = sbase;
    int n0 = b << 9;
    int nn = min(512, N_NODES - n0);

    lcnt[tid] = 0;
    lcnt[tid + 256] = 0;
    __syncthreads();
    for (int i = tid; i < m; i += 256) atomicAdd(&lcnt[bkt[base + i] >> 17], 1);
    __syncthreads();
    int a0 = lcnt[2 * tid], a1 = lcnt[2 * tid + 1];
    int pv = a0 + a1;
    ps[tid] = pv;
    __syncthreads();
    for (int d = 1; d < 256; d <<= 1) {
        int t = (tid >= d) ? ps[tid - d] : 0;
        __syncthreads();
        ps[tid] += t;
        __syncthreads();
    }
    int excl = ps[tid] - pv;
    loff[2 * tid] = excl;
    loff[2 * tid + 1] = excl + a0;
    lcur[2 * tid] = excl;
    lcur[2 * tid + 1] = excl + a0;
    __syncthreads();
    bool fit = (m <= BKCAP);
    for (int i = tid; i < m; i += 256) {
        int val = bkt[base + i];
        int dl = val >> 17;
        int p = atomicAdd(&lcur[dl], 1);
        if (fit) scsr[p] = val & 0x1FFFF;
        else csr[base + p] = val & 0x1FFFF;
    }
    __syncthreads();
    if (fit)
        for (int i = tid; i < m; i += 256) csr[base + i] = scsr[i];
    for (int i = tid; i < nn; i += 256)
        offpk[n0 + i] = (unsigned int)((base + loff[i]) | (lcnt[i] << 21));
}

// ---- gather: 4 edges per wave-iter, 16-deep unroll (4 int2 loads/lane) ----
__global__ void __launch_bounds__(256) gather_kernel(
        const ushort_t* __restrict__ hb, const unsigned int* __restrict__ offpk,
        const int* __restrict__ csr, ushort_t* __restrict__ aggb) {
    int node = blockIdx.x * 4 + (threadIdx.x >> 6);
    if (node >= N_NODES) return;
    int o = threadIdx.x & 63;
    int q4 = o >> 4;          // quarter 0..3 = edge slot
    int l = o & 15;           // channel group 4l..4l+3
    unsigned int v = offpk[node];
    int off0 = (int)(v & 0x1FFFFFu);
    int cnt = (int)(v >> 21);
    float a0 = 0.f, a1 = 0.f, a2 = 0.f, a3 = 0.f;
    int base = off0;
    int rem = cnt;
    while (rem > 0) {
        int take = min(rem, 64);
        int idxv = (o < take) ? csr[base + o] : 0;
        int j = 0;
        for (; j + 16 <= take; j += 16) {
            int i0 = __shfl(idxv, j + q4);
            int i1 = __shfl(idxv, j + 4 + q4);
            int i2 = __shfl(idxv, j + 8 + q4);
            int i3 = __shfl(idxv, j + 12 + q4);
            int2 u0 = ((const int2*)(hb + (size_t)i0 * HID))[l];
            int2 u1 = ((const int2*)(hb + (size_t)i1 * HID))[l];
            int2 u2 = ((const int2*)(hb + (size_t)i2 * HID))[l];
            int2 u3 = ((const int2*)(hb + (size_t)i3 * HID))[l];
            a0 += (blo(u0.x) + blo(u1.x)) + (blo(u2.x) + blo(u3.x));
            a1 += (bhi(u0.x) + bhi(u1.x)) + (bhi(u2.x) + bhi(u3.x));
            a2 += (blo(u0.y) + blo(u1.y)) + (blo(u2.y) + blo(u3.y));
            a3 += (bhi(u0.y) + bhi(u1.y)) + (bhi(u2.y) + bhi(u3.y));
        }
        for (; j < take; j += 4) {
            int e = j + q4;
            bool valid = (e < take);
            int idx = __shfl(idxv, valid ? e : 0);
            if (valid) {
                int2 u = ((const int2*)(hb + (size_t)idx * HID))[l];
                a0 += blo(u.x); a1 += bhi(u.x);
                a2 += blo(u.y); a3 += bhi(u.y);
            }
        }
        base += take;
        rem -= take;
    }
    a0 += __shfl_xor(a0, 16); a0 += __shfl_xor(a0, 32);
    a1 += __shfl_xor(a1, 16); a1 += __shfl_xor(a1, 32);
    a2 += __shfl_xor(a2, 16); a2 += __shfl_xor(a2, 32);
    a3 += __shfl_xor(a3, 16); a3 += __shfl_xor(a3, 32);
    if (o < 16) {
        float inv = 1.f / fmaxf((float)cnt, 1.f);
        ushort4 w;
        w.x = f2b(a0 * inv); w.y = f2b(a1 * inv);
        w.z = f2b(a2 * inv); w.w = f2b(a3 * inv);
        *(ushort4*)(aggb + (size_t)node * HID + l * 4) = w;
    }
}

// ---- layer v3 (MFMA): relu(agg@Wl + h@Wr + b) -> bf16 ---------------------
// 16x16x32 bf16 MFMA. Weights pre-swizzled into B-fragment order in LDS
// (B[k=quad*8+j][n=lane&15], 16B contiguous per lane); A/H tiles pitch 72
// (16B-aligned rows). Wave w owns nodes w*16..w*16+15; 4 n-tiles x 4 MFMA.
// C/D layout (verified m89/m91): col=lane&15, row=quad*4+reg.
__global__ void __launch_bounds__(256) layer_v3(
        const ushort_t* __restrict__ aggb, const ushort_t* __restrict__ rootb,
        const float* __restrict__ Wl, const float* __restrict__ Wr,
        const float* __restrict__ bias, ushort_t* outb) {
    __shared__ ushort_t sWlF[4096];
    __shared__ ushort_t sWrF[4096];
    __shared__ ushort_t sA[64 * MP];
    __shared__ ushort_t sH[64 * MP];
    __shared__ float sbias[HID];
    int tid = threadIdx.x;
    // stage weights into fragment order: idx = ((nt*2+ks)*64 + lane)*8 + j
    for (int idx = tid; idx < 4096; idx += 256) {
        int j = idx & 7;
        int ln = (idx >> 3) & 63;
        int t = idx >> 9;            // nt*2+ks
        int ks = t & 1, nt = t >> 1;
        int k = ks * 32 + (ln >> 4) * 8 + j;
        int n = nt * 16 + (ln & 15);
        sWlF[idx] = f2b(Wl[k * HID + n]);
        sWrF[idx] = f2b(Wr[k * HID + n]);
    }
    if (tid < HID) sbias[tid] = bias[tid];
    size_t tbase = (size_t)blockIdx.x * 64 * HID;
    {   // 512 int4 chunks, 2 per thread (overread lands in slack)
        const int4* ga = (const int4*)(aggb + tbase);
        const int4* gh = (const int4*)(rootb + tbase);
#pragma unroll
        for (int p = 0; p < 2; ++p) {
            int q = tid + 256 * p;
            int r = q >> 3, u = q & 7;
            *(int4*)(sA + r * MP + u * 8) = ga[q];
            *(int4*)(sH + r * MP + u * 8) = gh[q];
        }
    }
    __syncthreads();

    int wave = tid >> 6, lane = tid & 63;
    int quad = lane >> 4, col = lane & 15;
    int arow = wave * 16 + col;
    bf16x8 aA0 = *(const bf16x8*)(sA + arow * MP + quad * 8);
    bf16x8 aA1 = *(const bf16x8*)(sA + arow * MP + 32 + quad * 8);
    bf16x8 aH0 = *(const bf16x8*)(sH + arow * MP + quad * 8);
    bf16x8 aH1 = *(const bf16x8*)(sH + arow * MP + 32 + quad * 8);
    int node0 = blockIdx.x * 64;
#pragma unroll
    for (int nt = 0; nt < 4; ++nt) {
        f32x4 acc = {0.f, 0.f, 0.f, 0.f};
        const bf16x8* bl = (const bf16x8*)(sWlF + nt * 1024);
        const bf16x8* br = (const bf16x8*)(sWrF + nt * 1024);
        acc = __builtin_amdgcn_mfma_f32_16x16x32_bf16(aA0, bl[lane], acc, 0, 0, 0);
        acc = __builtin_amdgcn_mfma_f32_16x16x32_bf16(aA1, bl[64 + lane], acc, 0, 0, 0);
        acc = __builtin_amdgcn_mfma_f32_16x16x32_bf16(aH0, br[lane], acc, 0, 0, 0);
        acc = __builtin_amdgcn_mfma_f32_16x16x32_bf16(aH1, br[64 + lane], acc, 0, 0, 0);
        float bv = sbias[nt * 16 + col];
#pragma unroll
        for (int r = 0; r < 4; ++r) {
            int n = node0 + wave * 16 + quad * 4 + r;
            if (n < N_NODES)
                outb[(size_t)n * HID + nt * 16 + col] = f2b(fmaxf(acc[r] + bv, 0.f));
        }
    }
}

// ---- head v2: out = h @ Wlin + blin, LDS-tiled, fp32 out ------------------
__global__ void __launch_bounds__(256) head_v2(
        const ushort_t* __restrict__ hb, const float* __restrict__ W,
        const float* __restrict__ bias, float* __restrict__ out) {
    __shared__ float sWo[HID * OUT_CH];
    __shared__ ushort_t sH[64 * SAP];
    __shared__ float sb[OUT_CH];
    int tid = threadIdx.x;
    {
        const float4* W4 = (const float4*)W;
        float4* sW4 = (float4*)sWo;
        for (int i = tid; i < HID * OUT_CH / 4; i += 256) sW4[i] = W4[i];
    }
    if (tid < OUT_CH) sb[tid] = bias[tid];
    size_t tbase = (size_t)blockIdx.x * 64 * HID;
    {
        const int4* gh = (const int4*)(hb + tbase);
#pragma unroll
        for (int p = 0; p < 2; ++p) {
            int q = tid + 256 * p;
            int r = q >> 3, u = q & 7;
            *(int4*)(sH + r * SAP + u * 8) = gh[q];
        }
    }
    __syncthreads();

    int c0 = (tid & 7) << 2;
    int n0 = (tid >> 3) << 1;
    float acc[2][4];
#pragma unroll
    for (int i = 0; i < 2; ++i)
#pragma unroll
        for (int j = 0; j < 4; ++j) acc[i][j] = sb[c0 + j];

#pragma unroll 4
    for (int kk = 0; kk < 32; ++kk) {
        float4 w0 = *(const float4*)&sWo[(2 * kk) * OUT_CH + c0];
        float4 w1 = *(const float4*)&sWo[(2 * kk + 1) * OUT_CH + c0];
        const float* w0p = (const float*)&w0;
        const float* w1p = (const float*)&w1;
#pragma unroll
        for (int i = 0; i < 2; ++i) {
            unsigned uh = *(const unsigned*)(sH + (n0 + i) * SAP + 2 * kk);
            float h0 = blo(uh), h1 = bhi(uh);
#pragma unroll
            for (int j = 0; j < 4; ++j) acc[i][j] += h0 * w0p[j] + h1 * w1p[j];
        }
    }

    int node0 = blockIdx.x * 64;
#pragma unroll
    for (int i = 0; i < 2; ++i) {
        int n = node0 + n0 + i;
        if (n < N_NODES) {
            float4 o4;
            o4.x = acc[i][0]; o4.y = acc[i][1]; o4.z = acc[i][2]; o4.w = acc[i][3];
            *(float4*)(out + (size_t)n * OUT_CH + c0) = o4;
        }
    }
}

extern "C" void kernel_launch(void* const* d_in, const int* in_sizes, int n_in,
                              void* d_out, int out_size, void* d_ws, size_t ws_size,
                              hipStream_t stream) {
    const float* x    = (const float*)d_in[0];
    const int*   ei   = (const int*)d_in[1];
    const float* Wl1  = (const float*)d_in[2];
    const float* Wr1  = (const float*)d_in[3];
    const float* b1   = (const float*)d_in[4];
    const float* Wl2  = (const float*)d_in[5];
    const float* Wr2  = (const float*)d_in[6];
    const float* b2   = (const float*)d_in[7];
    const float* Wl3  = (const float*)d_in[8];
    const float* Wr3  = (const float*)d_in[9];
    const float* b3   = (const float*)d_in[10];
    const float* Wlin = (const float*)d_in[11];
    const float* blin = (const float*)d_in[12];
    float* out = (float*)d_out;

    // workspace layout (4-byte units), ~33 MB; tile overreads land in slack.
    int* ip              = (int*)d_ws;
    unsigned int* offpk  = (unsigned int*)ip;           // 100096
    int* btot            = (int*)(offpk + 100096);      // 256
    int* histG           = btot + 256;                  // NB*P = 200704
    int* csr             = histG + NB * P;              // 1600000
    ushort_t* aggb       = (ushort_t*)(csr + N_EDGES);  // 6.4M bf16 + 8192 slack
    ushort_t* featb      = aggb + 6408192;              // 6.4M bf16 + 8192 slack
    int* bkt             = (int*)aggb;  // bucket records alias aggb (dead until gather)

    const int GATHER_BLOCKS = (N_NODES + 3) / 4;         // 25000
    const int TILE_BLOCKS   = (N_NODES + 63) / 64;       // 1563

    // CSR build: convert+hist fused, scan, place, per-bucket fill
    convhist_kernel<<<CONV_BLOCKS, 256, 0, stream>>>(x, featb, ei, histG);
    scan_kernel<<<NB, 256, 0, stream>>>(histG, btot);
    place_kernel<<<P, 256, 0, stream>>>(ei, histG, btot, bkt);
    bucket_fill_kernel<<<NB, 256, 0, stream>>>(btot, bkt, csr, offpk);

    // layer 1 (root = bf16 x in featb; in-place featb output is block-local)
    gather_kernel<<<GATHER_BLOCKS, 256, 0, stream>>>(featb, offpk, csr, aggb);
    layer_v3<<<TILE_BLOCKS, 256, 0, stream>>>(aggb, featb, Wl1, Wr1, b1, featb);

    // layer 2
    gather_kernel<<<GATHER_BLOCKS, 256, 0, stream>>>(featb, offpk, csr, aggb);
    layer_v3<<<TILE_BLOCKS, 256, 0, stream>>>(aggb, featb, Wl2, Wr2, b2, featb);

    // layer 3
    gather_kernel<<<GATHER_BLOCKS, 256, 0, stream>>>(featb, offpk, csr, aggb);
    layer_v3<<<TILE_BLOCKS, 256, 0, stream>>>(aggb, featb, Wl3, Wr3, b3, featb);

    // head
    head_v2<<<TILE_BLOCKS, 256, 0, stream>>>(featb, Wlin, blin, out);
}